// Round 8
// baseline (576.772 us; speedup 1.0000x reference)
//
#include <hip/hip_runtime.h>
#include <hip/hip_bf16.h>

// Problem constants
#define B_    2
#define C_    256
#define T_    4096
#define GRP   32
#define CPG   8
#define NH    4
#define CH    64
#define K3C   768
#define SPLIT 4
#define GSL   8          // group-norm slices per group
#define NSTAT (B_ * GRP * GSL)   // 512
#define NCVT  128
#define NBLK  1024
#define LOG2E 1.4426950408889634f

typedef __attribute__((ext_vector_type(8))) short bf16x8;
typedef __attribute__((ext_vector_type(4))) float f32x4;
typedef __attribute__((ext_vector_type(16))) float f32x16;

#if __has_builtin(__builtin_amdgcn_exp2f)
#define EXP2(x) __builtin_amdgcn_exp2f(x)
#else
#define EXP2(x) exp2f(x)
#endif

__device__ __forceinline__ unsigned pk2(float a, float b) {
    __hip_bfloat162 h = __float22bfloat162_rn(make_float2(a, b));
    union { __hip_bfloat162 h2; unsigned u; } cv; cv.h2 = h;
    return cv.u;
}
__device__ __forceinline__ float bf2f(unsigned short u) {
    return __uint_as_float((unsigned)u << 16);
}

// Async global->LDS DMA, 16B per lane.  LDS dest = uniform base + lane*16.
__device__ __forceinline__ void gl_lds16(const unsigned short* g, unsigned short* l) {
    __builtin_amdgcn_global_load_lds(
        (const __attribute__((address_space(1))) unsigned int*)g,
        (__attribute__((address_space(3))) unsigned int*)l,
        16, 0, 0);
}

// Device-scope grid barrier.  gen read BEFORE arrival (ordering-critical);
// atomic-RMW spin (cross-XCD coherent); __threadfence for release/acquire.
// bar state zeroed by hipMemsetAsync each launch; each pair used once.
__device__ __forceinline__ void gbar(unsigned* cnt, unsigned* gen) {
    __syncthreads();
    if (threadIdx.x == 0) {
        __threadfence();
        unsigned g = atomicAdd(gen, 0u);
        if (atomicAdd(cnt, 1u) == NBLK - 1u) {
            __threadfence();
            atomicAdd(gen, 1u);
        } else {
            while (atomicAdd(gen, 0u) == g) { __builtin_amdgcn_s_sleep(8); }
            __threadfence();
        }
    }
    __syncthreads();
}

// Tiled layouts (coalescing, R7-validated):
//   xnT  : elem = ((b*256 + (t>>4))*32 + (c>>3))*128 + (t&15)*8 + (c&7)
//   Opart: elem = ((spbh*256 + (t>>4))*8 + (c>>3))*128 + (t&15)*8 + (c&7)

// ---------------------------------------------------------------------------
// ONE fused kernel: 5 phases separated by 4 grid barriers.
// grid 1024 x 256 = exactly 4 blocks/CU (LDS 33792 <= 40KB, VGPR capped by
// launch_bounds) -> co-residency guaranteed; removes 4 inter-kernel gaps.
// ---------------------------------------------------------------------------
__global__ __launch_bounds__(256, 4) void fused_kernel(
    const float* __restrict__ x,
    const float* __restrict__ norm_w, const float* __restrict__ norm_b,
    const float* __restrict__ qw, const float* __restrict__ qb_bias,
    const float* __restrict__ pw, const float* __restrict__ pb_bias,
    float* __restrict__ stat,
    unsigned short* __restrict__ qwb, unsigned short* __restrict__ pwb,
    unsigned short* __restrict__ xnT,
    unsigned short* __restrict__ q_t, unsigned short* __restrict__ k_t,
    unsigned short* __restrict__ v_d,
    unsigned short* __restrict__ Opart, float* __restrict__ lbuf,
    float* __restrict__ out, unsigned* __restrict__ bar) {

    __shared__ __align__(16) char raw[64 * 264 * 2];   // 33792 B, re-used per phase
    int blk = blockIdx.x;
    int tid = threadIdx.x;

    // ======================= Phase A: GN stats + weight cvt ================
    if (blk < NSTAT + NCVT) {
        if (blk < NSTAT) {
            int bg = blk >> 3, sl = blk & 7;
            const int SLN = CPG * T_ / GSL;        // 4096
            const float* xp = x + (size_t)bg * CPG * T_ + (size_t)sl * SLN;
            float s = 0.f, s2 = 0.f;
            for (int i = tid * 4; i < SLN; i += 1024) {
                float4 v = *(const float4*)&xp[i];
                s  += (v.x + v.y) + (v.z + v.w);
                s2 += (v.x * v.x + v.y * v.y) + (v.z * v.z + v.w * v.w);
            }
            for (int off = 32; off > 0; off >>= 1) {
                s  += __shfl_down(s,  off);
                s2 += __shfl_down(s2, off);
            }
            float* rs  = (float*)raw;
            float* rs2 = rs + 4;
            int wid = tid >> 6;
            if ((tid & 63) == 0) { rs[wid] = s; rs2[wid] = s2; }
            __syncthreads();
            if (tid == 0) {
                stat[blk * 2]     = (rs[0] + rs[1]) + (rs[2] + rs[3]);
                stat[blk * 2 + 1] = (rs2[0] + rs2[1]) + (rs2[2] + rs2[3]);
            }
        } else {
            int i = (blk - NSTAT) * 256 + tid;
            const int n1 = K3C * C_ / 8;
            const float* src; unsigned short* dst;
            if (i < n1) { src = qw + 8 * i; dst = qwb + 8 * i; }
            else { int j = i - n1; src = pw + 8 * j; dst = pwb + 8 * j; }
            float4 a = *(const float4*)src;
            float4 b = *(const float4*)(src + 4);
            uint4 u;
            u.x = pk2(a.x, a.y); u.y = pk2(a.z, a.w);
            u.z = pk2(b.x, b.y); u.w = pk2(b.z, b.w);
            *(uint4*)dst = u;
        }
    }
    gbar(&bar[0], &bar[1]);

    // ======================= Phase B: GroupNorm apply -> tiled xnT =========
    if (blk < 512) {
        int bg = blk & 63, sl = blk >> 6;
        int batch = bg / GRP, g = bg % GRP;
        const float* xp = x + (size_t)bg * CPG * T_;

        float s = 0.f, s2 = 0.f;
#pragma unroll
        for (int i = 0; i < GSL; ++i) {
            s  += stat[(bg * GSL + i) * 2];
            s2 += stat[(bg * GSL + i) * 2 + 1];
        }
        float inv_n = 1.f / (float)(CPG * T_);
        float mean = s * inv_n;
        float var  = s2 * inv_n - mean * mean;
        float inv  = rsqrtf(var + 1e-5f);

        float wv[8], bv[8];
#pragma unroll
        for (int j = 0; j < 8; j++) {
            float ww = norm_w[g * CPG + j] * inv;
            wv[j] = ww;
            bv[j] = norm_b[g * CPG + j] - mean * ww;
        }
        int t0 = sl * (T_ / GSL);
#pragma unroll
        for (int rep = 0; rep < 2; ++rep) {
            int t = t0 + rep * 256 + tid;
            float v[8];
#pragma unroll
            for (int j = 0; j < 8; j++) v[j] = xp[(size_t)j * T_ + t] * wv[j] + bv[j];
            uint4 u;
            u.x = pk2(v[0], v[1]); u.y = pk2(v[2], v[3]);
            u.z = pk2(v[4], v[5]); u.w = pk2(v[6], v[7]);
            *(uint4*)&xnT[(((size_t)batch * 256 + (t >> 4)) * 32 + g) * 128
                          + (t & 15) * 8] = u;
        }
    }
    gbar(&bar[2], &bar[3]);

    // ======================= Phase C: QKV GEMM =============================
    if (blk < 768) {
        int bx = blk & 31;
        int rem = blk >> 5;           // 0..23
        int by = rem % 12;
        int bz = rem / 12;
        int tb = bx * 128;
        int ob = by * 64;
        int l = tid & 15, oct = (tid >> 4) & 3, w = tid >> 6;

        unsigned short* SH = (unsigned short*)raw;   // 64 x 264

#pragma unroll
        for (int j = 0; j < 8; ++j) {
            int idx = tid + 256 * j;
            int row = idx >> 5, ch = idx & 31;
            *(uint4*)&SH[row * 264 + ch * 8] =
                *(const uint4*)&qwb[(size_t)(ob + row) * C_ + ch * 8];
        }
        __syncthreads();

        f32x4 acc[4][2];
#pragma unroll
        for (int mf = 0; mf < 4; ++mf)
#pragma unroll
            for (int nf = 0; nf < 2; ++nf) acc[mf][nf] = (f32x4){0.f, 0.f, 0.f, 0.f};

#pragma unroll
        for (int kk = 0; kk < 8; ++kk) {
            int c0 = 32 * kk + 8 * oct;
            bf16x8 bfr[2];
#pragma unroll
            for (int nf = 0; nf < 2; ++nf)
                bfr[nf] = *(const bf16x8*)
                    &xnT[(((size_t)bz * 256 + (tb >> 4) + 2 * w + nf) * 32
                         + 4 * kk + oct) * 128 + l * 8];
#pragma unroll
            for (int mf = 0; mf < 4; ++mf) {
                bf16x8 af = *(const bf16x8*)&SH[(16 * mf + l) * 264 + c0];
#pragma unroll
                for (int nf = 0; nf < 2; ++nf)
                    acc[mf][nf] = __builtin_amdgcn_mfma_f32_16x16x32_bf16(af, bfr[nf], acc[mf][nf], 0, 0, 0);
            }
        }

        int head = by / 3, sec = by - 3 * head;
        int bh = bz * NH + head;

        if (sec < 2) {
            float scale = (sec == 0) ? 0.125f * LOG2E : 1.f;
            unsigned short* dst = ((sec == 0) ? q_t : k_t) + (size_t)bh * T_ * CH;
#pragma unroll
            for (int mf = 0; mf < 4; ++mf) {
                float bvs[4];
#pragma unroll
                for (int r = 0; r < 4; ++r) bvs[r] = qb_bias[ob + 16 * mf + 4 * oct + r];
#pragma unroll
                for (int nf = 0; nf < 2; ++nf) {
                    int t = tb + 32 * w + 16 * nf + l;
                    float v0 = (acc[mf][nf][0] + bvs[0]) * scale;
                    float v1 = (acc[mf][nf][1] + bvs[1]) * scale;
                    float v2 = (acc[mf][nf][2] + bvs[2]) * scale;
                    float v3 = (acc[mf][nf][3] + bvs[3]) * scale;
                    uint2 u; u.x = pk2(v0, v1); u.y = pk2(v2, v3);
                    *(uint2*)&dst[(size_t)t * CH + 16 * mf + 4 * oct] = u;
                }
            }
        } else {
            __syncthreads();   // reuse SH as Vl[64][136]
#pragma unroll
            for (int mf = 0; mf < 4; ++mf) {
                float bvs[4];
#pragma unroll
                for (int r = 0; r < 4; ++r) bvs[r] = qb_bias[ob + 16 * mf + 4 * oct + r];
#pragma unroll
                for (int nf = 0; nf < 2; ++nf) {
                    int tl = 32 * w + 16 * nf + l;
#pragma unroll
                    for (int r = 0; r < 4; ++r) {
                        unsigned pv = pk2(acc[mf][nf][r] + bvs[r], 0.f);
                        SH[(16 * mf + 4 * oct + r) * 136 + tl] = (unsigned short)(pv & 0xffffu);
                    }
                }
            }
            __syncthreads();
            unsigned short* vdst = v_d + (size_t)bh * CH * T_;
#pragma unroll
            for (int j = 0; j < 4; ++j) {
                int idx = tid + 256 * j;
                int row = idx >> 4, ch = idx & 15;
                *(uint4*)&vdst[(size_t)row * T_ + tb + ch * 8] =
                    *(uint4*)&SH[row * 136 + ch * 8];
            }
        }
    }
    gbar(&bar[4], &bar[5]);

    // ======================= Phase D: flash attention ======================
    {
        int bx = blk & 31;
        int bh = (blk >> 5) & 7;
        int sp = blk >> 8;
        int t0 = bx * 128;
        int ln = tid & 63;
        int li = ln & 31;
        int hi = ln >> 5;
        int w  = tid >> 6;
        int l7 = li & 7;
        int sw = l7 ^ ((li >> 3) & 3);    // extended swizzle, SW(li)==SW(32+li)

        unsigned short* KtV = (unsigned short*)raw;  // Kt[2]:0..8191, Vt[2]:8192..16383 elems

        const unsigned short* qp = q_t + (size_t)bh * T_ * CH;
        const unsigned short* kp = k_t + (size_t)bh * T_ * CH;
        const unsigned short* vp = v_d + (size_t)bh * CH * T_;

        int tq = t0 + 32 * w + li;
        bf16x8 qf[4];
#pragma unroll
        for (int ks = 0; ks < 4; ++ks)
            qf[ks] = *(const bf16x8*)&qp[(size_t)tq * CH + ks * 16 + 8 * hi];

        int rsub = ln >> 3;
        int sch  = ln & 7;
        int cm8_0 = (sch ^ rsub ^ ((2 * w) & 3)) * 8;
        int cm8_1 = (sch ^ rsub ^ ((2 * w + 1) & 3)) * 8;
        int kr0 = 16 * w + rsub;

#define STAGE(buf, s0) do {                                                                  \
    gl_lds16(kp + (size_t)((s0) + kr0) * CH + cm8_0,     KtV + (buf) * 4096 + (16 * w) * 64);     \
    gl_lds16(kp + (size_t)((s0) + kr0 + 8) * CH + cm8_1, KtV + (buf) * 4096 + (16 * w + 8) * 64); \
    gl_lds16(vp + (size_t)kr0 * T_ + (s0) + cm8_0,       KtV + 8192 + (buf) * 4096 + (16 * w) * 64);     \
    gl_lds16(vp + (size_t)(kr0 + 8) * T_ + (s0) + cm8_1, KtV + 8192 + (buf) * 4096 + (16 * w + 8) * 64); \
} while (0)

        f32x16 O0, O1, Zv;
#pragma unroll
        for (int i = 0; i < 16; ++i) { O0[i] = 0.f; O1[i] = 0.f; Zv[i] = 0.f; }
        float l_run = 0.f;

        int s_beg = sp * (T_ / SPLIT);
        const int NT = (T_ / SPLIT) / 64;     // 16 tiles

        STAGE(0, s_beg);
        __syncthreads();

        int cur = 0;
        for (int t = 0; t < NT; ++t) {
            if (t + 1 < NT) STAGE(cur ^ 1, s_beg + (t + 1) * 64);
            const unsigned short* Ktc = KtV + cur * 4096;
            const unsigned short* Vtc = KtV + 8192 + cur * 4096;

            // ---- S^T = K^T Q (persistent-zero C for first MFMA) ----
            f32x16 S0, S1;
            __builtin_amdgcn_s_setprio(1);
            {
                bf16x8 ka0 = *(const bf16x8*)&Ktc[li * 64 + ((hi ^ sw) * 8)];
                bf16x8 ka1 = *(const bf16x8*)&Ktc[(32 + li) * 64 + ((hi ^ sw) * 8)];
                S0 = __builtin_amdgcn_mfma_f32_32x32x16_bf16(ka0, qf[0], Zv, 0, 0, 0);
                S1 = __builtin_amdgcn_mfma_f32_32x32x16_bf16(ka1, qf[0], Zv, 0, 0, 0);
            }
#pragma unroll
            for (int ks = 1; ks < 4; ++ks) {
                bf16x8 ka0 = *(const bf16x8*)
                    &Ktc[li * 64 + (((2 * ks + hi) ^ sw) * 8)];
                bf16x8 ka1 = *(const bf16x8*)
                    &Ktc[(32 + li) * 64 + (((2 * ks + hi) ^ sw) * 8)];
                S0 = __builtin_amdgcn_mfma_f32_32x32x16_bf16(ka0, qf[ks], S0, 0, 0, 0);
                S1 = __builtin_amdgcn_mfma_f32_32x32x16_bf16(ka1, qf[ks], S1, 0, 0, 0);
            }
            __builtin_amdgcn_s_setprio(0);

            // ---- p = exp2(S) -> bf16 pairs; lane-local l partial ----
            unsigned W0[8], W1[8];
            float lloc = 0.f;
#pragma unroll
            for (int h = 0; h < 4; ++h) {
                float a0 = EXP2(S0[4 * h + 0]), a1 = EXP2(S0[4 * h + 1]);
                float a2 = EXP2(S0[4 * h + 2]), a3 = EXP2(S0[4 * h + 3]);
                float b0 = EXP2(S1[4 * h + 0]), b1 = EXP2(S1[4 * h + 1]);
                float b2 = EXP2(S1[4 * h + 2]), b3 = EXP2(S1[4 * h + 3]);
                lloc += ((a0 + a1) + (a2 + a3)) + ((b0 + b1) + (b2 + b3));
                W0[2 * h] = pk2(a0, a1); W0[2 * h + 1] = pk2(a2, a3);
                W1[2 * h] = pk2(b0, b1); W1[2 * h + 1] = pk2(b2, b3);
            }
            l_run += lloc;

            // ---- O^T += V P^T; P B-frags via permlane32_swap ----
            __builtin_amdgcn_s_setprio(1);
#pragma unroll
            for (int g = 0; g < 4; ++g) {
                int ks = g & 1;
                unsigned w0, w1, w2, w3;
                if (g < 2) {
                    w0 = W0[4 * ks + 0]; w1 = W0[4 * ks + 1];
                    w2 = W0[4 * ks + 2]; w3 = W0[4 * ks + 3];
                } else {
                    w0 = W1[4 * ks + 0]; w1 = W1[4 * ks + 1];
                    w2 = W1[4 * ks + 2]; w3 = W1[4 * ks + 3];
                }
                asm("v_permlane32_swap_b32 %0, %1" : "+v"(w0), "+v"(w2));
                asm("v_permlane32_swap_b32 %0, %1" : "+v"(w1), "+v"(w3));
                union { unsigned u[4]; bf16x8 v; } pu;
                pu.u[0] = w0; pu.u[1] = w1; pu.u[2] = w2; pu.u[3] = w3;
                bf16x8 va0 = *(const bf16x8*)
                    &Vtc[li * 64 + (((2 * g + hi) ^ sw) * 8)];
                bf16x8 va1 = *(const bf16x8*)
                    &Vtc[(32 + li) * 64 + (((2 * g + hi) ^ sw) * 8)];
                O0 = __builtin_amdgcn_mfma_f32_32x32x16_bf16(va0, pu.v, O0, 0, 0, 0);
                O1 = __builtin_amdgcn_mfma_f32_32x32x16_bf16(va1, pu.v, O1, 0, 0, 0);
            }
            __builtin_amdgcn_s_setprio(0);

            __syncthreads();
            cur ^= 1;
        }
#undef STAGE

        // ---- final l reduce + store normalized partials (tiled Opart) ----
        float lt = l_run + __shfl_xor(l_run, 32);
        float inv = 1.f / lt;
        size_t obase = ((size_t)(sp * 8 + bh) * 256 + (tq >> 4)) * 8;
        int ti = tq & 15;
#pragma unroll
        for (int cb = 0; cb < 2; ++cb) {
#pragma unroll
            for (int h = 0; h < 4; ++h) {
                float v0, v1, v2, v3;
                if (cb == 0) {
                    v0 = O0[4 * h + 0]; v1 = O0[4 * h + 1];
                    v2 = O0[4 * h + 2]; v3 = O0[4 * h + 3];
                } else {
                    v0 = O1[4 * h + 0]; v1 = O1[4 * h + 1];
                    v2 = O1[4 * h + 2]; v3 = O1[4 * h + 3];
                }
                uint2 u;
                u.x = pk2(v0 * inv, v1 * inv);
                u.y = pk2(v2 * inv, v3 * inv);
                *(uint2*)&Opart[(obase + 4 * cb + h) * 128 + ti * 8 + 4 * hi] = u;
            }
        }
        if (hi == 0) lbuf[(size_t)(sp * 8 + bh) * T_ + tq] = lt;
    }
    gbar(&bar[6], &bar[7]);

    // ======================= Phase E: proj GEMM + combine + residual =======
    if (blk < 512) {
        int tb = (blk & 63) * 64;
        int ob = ((blk >> 6) & 3) * 64;
        int bz = blk >> 8;
        int l = tid & 15, oct = (tid >> 4) & 3, w = tid >> 6;

        unsigned short* SH = (unsigned short*)raw;

#pragma unroll
        for (int j = 0; j < 8; ++j) {
            int idx = tid + 256 * j;
            int row = idx >> 5, ch = idx & 31;
            *(uint4*)&SH[row * 264 + ch * 8] =
                *(const uint4*)&pwb[(size_t)(ob + row) * C_ + ch * 8];
        }
        __syncthreads();

        int t = tb + 16 * w + l;

        float lwn[SPLIT][NH];
#pragma unroll
        for (int h = 0; h < NH; ++h) {
            float lw[SPLIT], lsum = 0.f;
#pragma unroll
            for (int sp = 0; sp < SPLIT; ++sp) {
                lw[sp] = lbuf[(size_t)(sp * 8 + bz * NH + h) * T_ + t];
                lsum += lw[sp];
            }
            float inv = 1.f / lsum;
#pragma unroll
            for (int sp = 0; sp < SPLIT; ++sp) lwn[sp][h] = lw[sp] * inv;
        }

        f32x4 acc[4];
#pragma unroll
        for (int mf = 0; mf < 4; ++mf) acc[mf] = (f32x4){0.f, 0.f, 0.f, 0.f};

#pragma unroll
        for (int kk = 0; kk < 8; ++kk) {
            int c0 = 32 * kk + 8 * oct;
            int h  = kk >> 1;
            int cc = 4 * (kk & 1) + oct;

            float o[8];
#pragma unroll
            for (int j = 0; j < 8; ++j) o[j] = 0.f;
#pragma unroll
            for (int sp = 0; sp < SPLIT; ++sp) {
                const unsigned short* p = Opart +
                    (((size_t)(sp * 8 + bz * NH + h) * 256 + (t >> 4)) * 8 + cc) * 128
                    + (t & 15) * 8;
                uint4 u = *(const uint4*)p;
                float s = lwn[sp][h];
                o[0] += bf2f((unsigned short)(u.x & 0xffffu)) * s;
                o[1] += bf2f((unsigned short)(u.x >> 16)) * s;
                o[2] += bf2f((unsigned short)(u.y & 0xffffu)) * s;
                o[3] += bf2f((unsigned short)(u.y >> 16)) * s;
                o[4] += bf2f((unsigned short)(u.z & 0xffffu)) * s;
                o[5] += bf2f((unsigned short)(u.z >> 16)) * s;
                o[6] += bf2f((unsigned short)(u.w & 0xffffu)) * s;
                o[7] += bf2f((unsigned short)(u.w >> 16)) * s;
            }
            union { uint4 u; bf16x8 v; } pb;
            pb.u.x = pk2(o[0], o[1]); pb.u.y = pk2(o[2], o[3]);
            pb.u.z = pk2(o[4], o[5]); pb.u.w = pk2(o[6], o[7]);

#pragma unroll
            for (int mf = 0; mf < 4; ++mf) {
                bf16x8 af = *(const bf16x8*)&SH[(16 * mf + l) * 264 + c0];
                acc[mf] = __builtin_amdgcn_mfma_f32_16x16x32_bf16(af, pb.v, acc[mf], 0, 0, 0);
            }
        }

#pragma unroll
        for (int mf = 0; mf < 4; ++mf) {
#pragma unroll
            for (int r = 0; r < 4; ++r) {
                int o = ob + 16 * mf + 4 * oct + r;
                size_t idx = ((size_t)bz * C_ + o) * T_ + t;
                out[idx] = acc[mf][r] + pb_bias[o] + x[idx];
            }
        }
    }
}

// ---------------------------------------------------------------------------
extern "C" void kernel_launch(void* const* d_in, const int* in_sizes, int n_in,
                              void* d_out, int out_size, void* d_ws, size_t ws_size,
                              hipStream_t stream) {
    const float* x      = (const float*)d_in[0];
    const float* norm_w = (const float*)d_in[1];
    const float* norm_b = (const float*)d_in[2];
    const float* qkv_w  = (const float*)d_in[3];
    const float* qkv_b  = (const float*)d_in[4];
    const float* proj_w = (const float*)d_in[5];
    const float* proj_b = (const float*)d_in[6];
    float* out = (float*)d_out;

    char* p = (char*)d_ws;
    unsigned short* xnT = (unsigned short*)p; p += (size_t)B_ * T_ * C_ * 2;        // 4 MB
    unsigned short* qwb = (unsigned short*)p; p += (size_t)K3C * C_ * 2;            // 384 KB
    unsigned short* pwb = (unsigned short*)p; p += (size_t)C_ * C_ * 2;             // 128 KB
    unsigned short* q_t = (unsigned short*)p; p += (size_t)B_ * NH * T_ * CH * 2;   // 4 MB
    unsigned short* k_t = (unsigned short*)p; p += (size_t)B_ * NH * T_ * CH * 2;   // 4 MB
    unsigned short* v_d = (unsigned short*)p; p += (size_t)B_ * NH * T_ * CH * 2;   // 4 MB
    unsigned short* Opart = (unsigned short*)p; p += (size_t)SPLIT * 8 * T_ * CH * 2; // 16 MB
    float* lbuf         = (float*)p;          p += (size_t)SPLIT * 8 * T_ * 4;      // 512 KB
    float* stat         = (float*)p;          p += (size_t)NSTAT * 2 * 4;           // 4 KB
    unsigned* bar       = (unsigned*)p;       p += 64;

    hipMemsetAsync(bar, 0, 64, stream);
    fused_kernel<<<dim3(NBLK), dim3(256), 0, stream>>>(
        x, norm_w, norm_b, qkv_w, qkv_b, proj_w, proj_b,
        stat, qwb, pwb, xnT, q_t, k_t, v_d, Opart, lbuf, out, bar);
}

// Round 9
// 134.025 us; speedup vs baseline: 4.3035x; 4.3035x over previous
//
#include <hip/hip_runtime.h>
#include <hip/hip_bf16.h>

// Problem constants
#define B_    2
#define C_    256
#define T_    4096
#define GRP   32
#define CPG   8
#define NH    4
#define CH    64
#define K3C   768
#define SPLIT 4
#define GSL   8          // group-norm slices per group
#define NSTAT (B_ * GRP * GSL)   // 512
#define NCVT  128
#define LOG2E 1.4426950408889634f

typedef __attribute__((ext_vector_type(8))) short bf16x8;
typedef __attribute__((ext_vector_type(4))) float f32x4;
typedef __attribute__((ext_vector_type(16))) float f32x16;

#if __has_builtin(__builtin_amdgcn_exp2f)
#define EXP2(x) __builtin_amdgcn_exp2f(x)
#else
#define EXP2(x) exp2f(x)
#endif

__device__ __forceinline__ unsigned pk2(float a, float b) {
    __hip_bfloat162 h = __float22bfloat162_rn(make_float2(a, b));
    union { __hip_bfloat162 h2; unsigned u; } cv; cv.h2 = h;
    return cv.u;
}
__device__ __forceinline__ float bf2f(unsigned short u) {
    return __uint_as_float((unsigned)u << 16);
}

// Async global->LDS DMA, 16B per lane.  LDS dest = uniform base + lane*16.
__device__ __forceinline__ void gl_lds16(const unsigned short* g, unsigned short* l) {
    __builtin_amdgcn_global_load_lds(
        (const __attribute__((address_space(1))) unsigned int*)g,
        (__attribute__((address_space(3))) unsigned int*)l,
        16, 0, 0);
}

// Tiled layouts (coalescing fix, R7-validated):
//   xnT  : elem offset = ((b*256 + (t>>4))*32 + (c>>3))*128 + (t&15)*8 + (c&7)
//   Opart: elem offset = ((spbh*256 + (t>>4))*8 + (c>>3))*128 + (t&15)*8 + (c&7)

// ---------------------------------------------------------------------------
// Kernel 0: fused GroupNorm stats (blocks 0..511) + weight cvt (512..639).
// ---------------------------------------------------------------------------
__global__ __launch_bounds__(256) void pre_kernel(
    const float* __restrict__ x, float* __restrict__ stat,
    const float* __restrict__ qw, const float* __restrict__ pw,
    unsigned short* __restrict__ qwb, unsigned short* __restrict__ pwb) {
    int bid = blockIdx.x;
    int tid = threadIdx.x;
    if (bid < NSTAT) {
        int bg = bid >> 3, sl = bid & 7;
        const int SLN = CPG * T_ / GSL;        // 4096
        const float* xp = x + (size_t)bg * CPG * T_ + (size_t)sl * SLN;
        float s = 0.f, s2 = 0.f;
        for (int i = tid * 4; i < SLN; i += 1024) {
            float4 v = *(const float4*)&xp[i];
            s  += (v.x + v.y) + (v.z + v.w);
            s2 += (v.x * v.x + v.y * v.y) + (v.z * v.z + v.w * v.w);
        }
        for (int off = 32; off > 0; off >>= 1) {
            s  += __shfl_down(s,  off);
            s2 += __shfl_down(s2, off);
        }
        __shared__ float rs[4], rs2[4];
        int wid = tid >> 6;
        if ((tid & 63) == 0) { rs[wid] = s; rs2[wid] = s2; }
        __syncthreads();
        if (tid == 0) {
            stat[bid * 2]     = (rs[0] + rs[1]) + (rs[2] + rs[3]);
            stat[bid * 2 + 1] = (rs2[0] + rs2[1]) + (rs2[2] + rs2[3]);
        }
    } else {
        int i = (bid - NSTAT) * 256 + tid;
        const int n1 = K3C * C_ / 8;
        const float* src; unsigned short* dst;
        if (i < n1) { src = qw + 8 * i; dst = qwb + 8 * i; }
        else { int j = i - n1; src = pw + 8 * j; dst = pwb + 8 * j; }
        float4 a = *(const float4*)src;
        float4 b = *(const float4*)(src + 4);
        uint4 u;
        u.x = pk2(a.x, a.y); u.y = pk2(a.z, a.w);
        u.z = pk2(b.x, b.y); u.w = pk2(b.z, b.w);
        *(uint4*)dst = u;
    }
}

// ---------------------------------------------------------------------------
// Kernel 1: GroupNorm apply -> bf16 TILED xnT (coalesced 256B-run writes).
// ---------------------------------------------------------------------------
__global__ __launch_bounds__(256) void gn_apply_kernel(
    const float* __restrict__ x, const float* __restrict__ stat,
    const float* __restrict__ w, const float* __restrict__ b,
    unsigned short* __restrict__ xnT) {
    int bg = blockIdx.x, sl = blockIdx.y;
    int batch = bg / GRP, g = bg % GRP;
    const float* xp = x + (size_t)bg * CPG * T_;
    int tid = threadIdx.x;

    float s = 0.f, s2 = 0.f;
#pragma unroll
    for (int i = 0; i < GSL; ++i) {
        s  += stat[(bg * GSL + i) * 2];
        s2 += stat[(bg * GSL + i) * 2 + 1];
    }
    float inv_n = 1.f / (float)(CPG * T_);
    float mean = s * inv_n;
    float var  = s2 * inv_n - mean * mean;
    float inv  = rsqrtf(var + 1e-5f);

    float wv[8], bv[8];
#pragma unroll
    for (int j = 0; j < 8; j++) {
        float ww = w[g * CPG + j] * inv;
        wv[j] = ww;
        bv[j] = b[g * CPG + j] - mean * ww;
    }
    int t0 = sl * (T_ / GSL);
#pragma unroll
    for (int rep = 0; rep < 2; ++rep) {
        int t = t0 + rep * 256 + tid;
        float v[8];
#pragma unroll
        for (int j = 0; j < 8; j++) v[j] = xp[(size_t)j * T_ + t] * wv[j] + bv[j];
        uint4 u;
        u.x = pk2(v[0], v[1]); u.y = pk2(v[2], v[3]);
        u.z = pk2(v[4], v[5]); u.w = pk2(v[6], v[7]);
        *(uint4*)&xnT[(((size_t)batch * 256 + (t >> 4)) * 32 + g) * 128
                      + (t & 15) * 8] = u;
    }
}

// ---------------------------------------------------------------------------
// Kernel 2: QKV GEMM.  W-tile in LDS; X B-frags from TILED xnT -> each wave
// load is a fully contiguous 1KB (lanes l:+16B, oct:+256B).  grid(32,12,2).
// ---------------------------------------------------------------------------
__global__ __launch_bounds__(256) void qkv_gemm_kernel(
    const unsigned short* __restrict__ Wb, const float* __restrict__ bias,
    const unsigned short* __restrict__ Xt, unsigned short* __restrict__ q_t,
    unsigned short* __restrict__ k_t, unsigned short* __restrict__ v_d) {
    int tb = blockIdx.x * 128;
    int by = blockIdx.y;
    int bz = blockIdx.z;
    int ob = by * 64;
    int tid = threadIdx.x;
    int l = tid & 15, oct = (tid >> 4) & 3, w = tid >> 6;

    __shared__ __align__(16) unsigned short SH[64 * 264];

#pragma unroll
    for (int j = 0; j < 8; ++j) {
        int idx = tid + 256 * j;
        int row = idx >> 5, ch = idx & 31;
        *(uint4*)&SH[row * 264 + ch * 8] =
            *(const uint4*)&Wb[(size_t)(ob + row) * C_ + ch * 8];
    }
    __syncthreads();

    f32x4 acc[4][2];
#pragma unroll
    for (int mf = 0; mf < 4; ++mf)
#pragma unroll
        for (int nf = 0; nf < 2; ++nf) acc[mf][nf] = (f32x4){0.f, 0.f, 0.f, 0.f};

#pragma unroll
    for (int kk = 0; kk < 8; ++kk) {
        int c0 = 32 * kk + 8 * oct;
        bf16x8 bfr[2];
#pragma unroll
        for (int nf = 0; nf < 2; ++nf)
            bfr[nf] = *(const bf16x8*)
                &Xt[(((size_t)bz * 256 + (tb >> 4) + 2 * w + nf) * 32
                     + 4 * kk + oct) * 128 + l * 8];
#pragma unroll
        for (int mf = 0; mf < 4; ++mf) {
            bf16x8 af = *(const bf16x8*)&SH[(16 * mf + l) * 264 + c0];
#pragma unroll
            for (int nf = 0; nf < 2; ++nf)
                acc[mf][nf] = __builtin_amdgcn_mfma_f32_16x16x32_bf16(af, bfr[nf], acc[mf][nf], 0, 0, 0);
        }
    }

    int head = by / 3, sec = by - 3 * head;
    int bh = bz * NH + head;

    if (sec < 2) {
        float scale = (sec == 0) ? 0.125f * LOG2E : 1.f;
        unsigned short* dst = ((sec == 0) ? q_t : k_t) + (size_t)bh * T_ * CH;
#pragma unroll
        for (int mf = 0; mf < 4; ++mf) {
            float bvs[4];
#pragma unroll
            for (int r = 0; r < 4; ++r) bvs[r] = bias[ob + 16 * mf + 4 * oct + r];
#pragma unroll
            for (int nf = 0; nf < 2; ++nf) {
                int t = tb + 32 * w + 16 * nf + l;
                float v0 = (acc[mf][nf][0] + bvs[0]) * scale;
                float v1 = (acc[mf][nf][1] + bvs[1]) * scale;
                float v2 = (acc[mf][nf][2] + bvs[2]) * scale;
                float v3 = (acc[mf][nf][3] + bvs[3]) * scale;
                uint2 u; u.x = pk2(v0, v1); u.y = pk2(v2, v3);
                *(uint2*)&dst[(size_t)t * CH + 16 * mf + 4 * oct] = u;
            }
        }
    } else {
        __syncthreads();   // reuse SH as Vl[64][136]
#pragma unroll
        for (int mf = 0; mf < 4; ++mf) {
            float bvs[4];
#pragma unroll
            for (int r = 0; r < 4; ++r) bvs[r] = bias[ob + 16 * mf + 4 * oct + r];
#pragma unroll
            for (int nf = 0; nf < 2; ++nf) {
                int tl = 32 * w + 16 * nf + l;
#pragma unroll
                for (int r = 0; r < 4; ++r) {
                    unsigned pv = pk2(acc[mf][nf][r] + bvs[r], 0.f);
                    SH[(16 * mf + 4 * oct + r) * 136 + tl] = (unsigned short)(pv & 0xffffu);
                }
            }
        }
        __syncthreads();
        unsigned short* vdst = v_d + (size_t)bh * CH * T_;
#pragma unroll
        for (int j = 0; j < 4; ++j) {
            int idx = tid + 256 * j;
            int row = idx >> 4, ch = idx & 15;
            *(uint4*)&vdst[(size_t)row * T_ + tb + ch * 8] =
                *(uint4*)&SH[row * 136 + ch * 8];
        }
    }
}

// ---------------------------------------------------------------------------
// Kernel 3: flash attention (R7 structure + VALU cuts):
//  - persistent zero vector Zv as C-in for the first MFMA of each S block
//    (removes 32 v_mov/tile of accumulator zero-init)
//  - tile loop unrolled x2 so buffer parity is compile-time: all ds_read
//    addresses are 8 precomputed lane bases + constant offset immediates
//    (+4096B row-32, +8192B buffer1) -> no per-tile address VALU.
// Extended swizzle SW(r)=(r&7)^((r>>3)&3): 0 bank conflicts (R6/R7-validated).
// 32KB LDS, grid 1024 = 4 blocks/CU exact fill.
// ---------------------------------------------------------------------------
__global__ __launch_bounds__(256, 4) void attn_kernel(
    const unsigned short* __restrict__ q_t, const unsigned short* __restrict__ k_t,
    const unsigned short* __restrict__ v_d, unsigned short* __restrict__ Opart,
    float* __restrict__ lbuf) {
    int bh = blockIdx.y;
    int sp = blockIdx.z;
    int t0 = blockIdx.x * 128;
    int tid = threadIdx.x;
    int ln = tid & 63;                    // lane in wave
    int li = ln & 31;                     // row/col within 32
    int hi = ln >> 5;                     // half-wave
    int w  = tid >> 6;                    // wave id 0..3
    int l7 = li & 7;
    int sw = l7 ^ ((li >> 3) & 3);        // SW(li) == SW(32+li)

    __shared__ __align__(16) unsigned short Kt[2][64 * 64];  // [s][c] ext-swizzled
    __shared__ __align__(16) unsigned short Vt[2][64 * 64];  // [c][s] ext-swizzled

    const unsigned short* qb = q_t + (size_t)bh * T_ * CH;
    const unsigned short* kb = k_t + (size_t)bh * T_ * CH;
    const unsigned short* vb = v_d + (size_t)bh * CH * T_;

    // Q B-frags: col t = li, k(c) = 16*ks + 8*hi + j  (contiguous 16B)
    int tq = t0 + 32 * w + li;
    bf16x8 qf[4];
#pragma unroll
    for (int ks = 0; ks < 4; ++ks)
        qf[ks] = *(const bf16x8*)&qb[(size_t)tq * CH + ks * 16 + 8 * hi];

    // Precomputed LDS read bases (buffer 0); +2048 elems = row 32+li,
    // +4096 elems = buffer 1 -> all constant ds_read offset immediates.
    const unsigned short* kbp[4];
    const unsigned short* vbp[4];
#pragma unroll
    for (int ks = 0; ks < 4; ++ks) {
        int co = ((2 * ks + hi) ^ sw) * 8;
        kbp[ks] = &Kt[0][li * 64 + co];
        vbp[ks] = &Vt[0][li * 64 + co];
    }

    // staging: lane ln stages row kr0(+8), phys chunk sch; source content
    // chunk = sch ^ SW(row)
    int rsub = ln >> 3;
    int sch  = ln & 7;
    int cm8_0 = (sch ^ rsub ^ ((2 * w) & 3)) * 8;
    int cm8_1 = (sch ^ rsub ^ ((2 * w + 1) & 3)) * 8;
    int kr0 = 16 * w + rsub;

#define STAGE(buf, s0) do {                                                            \
    gl_lds16(kb + (size_t)((s0) + kr0) * CH + cm8_0,     &Kt[buf][(16 * w) * 64]);     \
    gl_lds16(kb + (size_t)((s0) + kr0 + 8) * CH + cm8_1, &Kt[buf][(16 * w + 8) * 64]); \
    gl_lds16(vb + (size_t)kr0 * T_ + (s0) + cm8_0,       &Vt[buf][(16 * w) * 64]);     \
    gl_lds16(vb + (size_t)(kr0 + 8) * T_ + (s0) + cm8_1, &Vt[buf][(16 * w + 8) * 64]); \
} while (0)

    f32x16 O0, O1, Zv;
#pragma unroll
    for (int i = 0; i < 16; ++i) { O0[i] = 0.f; O1[i] = 0.f; Zv[i] = 0.f; }
    float l_run = 0.f;

    int s_beg = sp * (T_ / SPLIT);
    const int NT = (T_ / SPLIT) / 64;     // 16 tiles (even)

    STAGE(0, s_beg);
    __syncthreads();

// one tile body; OFS = 0 (buffer 0) or 4096 (buffer 1), compile-time
#define TILE(OFS) do {                                                                 \
        f32x16 S0, S1;                                                                 \
        __builtin_amdgcn_s_setprio(1);                                                 \
        {                                                                              \
            bf16x8 ka0 = *(const bf16x8*)(kbp[0] + (OFS));                             \
            bf16x8 ka1 = *(const bf16x8*)(kbp[0] + (OFS) + 2048);                      \
            S0 = __builtin_amdgcn_mfma_f32_32x32x16_bf16(ka0, qf[0], Zv, 0, 0, 0);     \
            S1 = __builtin_amdgcn_mfma_f32_32x32x16_bf16(ka1, qf[0], Zv, 0, 0, 0);     \
        }                                                                              \
        _Pragma("unroll")                                                              \
        for (int ks = 1; ks < 4; ++ks) {                                               \
            bf16x8 ka0 = *(const bf16x8*)(kbp[ks] + (OFS));                            \
            bf16x8 ka1 = *(const bf16x8*)(kbp[ks] + (OFS) + 2048);                     \
            S0 = __builtin_amdgcn_mfma_f32_32x32x16_bf16(ka0, qf[ks], S0, 0, 0, 0);    \
            S1 = __builtin_amdgcn_mfma_f32_32x32x16_bf16(ka1, qf[ks], S1, 0, 0, 0);    \
        }                                                                              \
        __builtin_amdgcn_s_setprio(0);                                                 \
        unsigned W0[8], W1[8];                                                         \
        float lloc = 0.f;                                                              \
        _Pragma("unroll")                                                              \
        for (int h = 0; h < 4; ++h) {                                                  \
            float a0 = EXP2(S0[4 * h + 0]), a1 = EXP2(S0[4 * h + 1]);                  \
            float a2 = EXP2(S0[4 * h + 2]), a3 = EXP2(S0[4 * h + 3]);                  \
            float b0 = EXP2(S1[4 * h + 0]), b1 = EXP2(S1[4 * h + 1]);                  \
            float b2 = EXP2(S1[4 * h + 2]), b3 = EXP2(S1[4 * h + 3]);                  \
            lloc += ((a0 + a1) + (a2 + a3)) + ((b0 + b1) + (b2 + b3));                 \
            W0[2 * h] = pk2(a0, a1); W0[2 * h + 1] = pk2(a2, a3);                      \
            W1[2 * h] = pk2(b0, b1); W1[2 * h + 1] = pk2(b2, b3);                      \
        }                                                                              \
        l_run += lloc;                                                                 \
        __builtin_amdgcn_s_setprio(1);                                                 \
        _Pragma("unroll")                                                              \
        for (int g = 0; g < 4; ++g) {                                                  \
            int ks = g & 1;                                                            \
            unsigned w0, w1, w2, w3;                                                   \
            if (g < 2) {                                                               \
                w0 = W0[4 * ks + 0]; w1 = W0[4 * ks + 1];                              \
                w2 = W0[4 * ks + 2]; w3 = W0[4 * ks + 3];                              \
            } else {                                                                   \
                w0 = W1[4 * ks + 0]; w1 = W1[4 * ks + 1];                              \
                w2 = W1[4 * ks + 2]; w3 = W1[4 * ks + 3];                              \
            }                                                                          \
            asm("v_permlane32_swap_b32 %0, %1" : "+v"(w0), "+v"(w2));                  \
            asm("v_permlane32_swap_b32 %0, %1" : "+v"(w1), "+v"(w3));                  \
            union { unsigned u[4]; bf16x8 v; } pu;                                     \
            pu.u[0] = w0; pu.u[1] = w1; pu.u[2] = w2; pu.u[3] = w3;                    \
            bf16x8 va0 = *(const bf16x8*)(vbp[g] + (OFS));                             \
            bf16x8 va1 = *(const bf16x8*)(vbp[g] + (OFS) + 2048);                      \
            O0 = __builtin_amdgcn_mfma_f32_32x32x16_bf16(va0, pu.v, O0, 0, 0, 0);      \
            O1 = __builtin_amdgcn_mfma_f32_32x32x16_bf16(va1, pu.v, O1, 0, 0, 0);      \
        }                                                                              \
        __builtin_amdgcn_s_setprio(0);                                                 \
    } while (0)

    for (int tt = 0; tt < NT / 2; ++tt) {
        int te = 2 * tt;
        // even tile: buffer 0; stage next into buffer 1
        if (te + 1 < NT) STAGE(1, s_beg + (te + 1) * 64);
        TILE(0);
        __syncthreads();
        // odd tile: buffer 1; stage next into buffer 0
        if (te + 2 < NT) STAGE(0, s_beg + (te + 2) * 64);
        TILE(4096);
        __syncthreads();
    }
#undef TILE
#undef STAGE

    // ---- final l reduce + store normalized partials bf16 (TILED Opart) ----
    float lt = l_run + __shfl_xor(l_run, 32);
    float inv = 1.f / lt;
    size_t obase = ((size_t)(sp * 8 + bh) * 256 + (tq >> 4)) * 8;
    int ti = tq & 15;
#pragma unroll
    for (int cb = 0; cb < 2; ++cb) {
#pragma unroll
        for (int h = 0; h < 4; ++h) {
            float v0, v1, v2, v3;
            if (cb == 0) {
                v0 = O0[4 * h + 0]; v1 = O0[4 * h + 1];
                v2 = O0[4 * h + 2]; v3 = O0[4 * h + 3];
            } else {
                v0 = O1[4 * h + 0]; v1 = O1[4 * h + 1];
                v2 = O1[4 * h + 2]; v3 = O1[4 * h + 3];
            }
            uint2 u;
            u.x = pk2(v0 * inv, v1 * inv);
            u.y = pk2(v2 * inv, v3 * inv);
            *(uint2*)&Opart[(obase + 4 * cb + h) * 128 + ti * 8 + 4 * hi] = u;
        }
    }
    if (hi == 0) lbuf[(size_t)(sp * 8 + bh) * T_ + tq] = lt;
}

// ---------------------------------------------------------------------------
// Kernel 4: proj GEMM + FUSED combine + bias + residual -> fp32 out.
// Opart read from TILED layout -> contiguous 1KB per wave instruction.
// ---------------------------------------------------------------------------
__global__ __launch_bounds__(256) void proj_gemm_kernel(
    const unsigned short* __restrict__ Wb, const float* __restrict__ bias,
    const unsigned short* __restrict__ Opart, const float* __restrict__ lbuf,
    const float* __restrict__ xres, float* __restrict__ out) {
    int tb = blockIdx.x * 64;
    int ob = blockIdx.y * 64;
    int bz = blockIdx.z;
    int tid = threadIdx.x;
    int l = tid & 15, oct = (tid >> 4) & 3, w = tid >> 6;

    __shared__ __align__(16) unsigned short SH[64 * 264];

#pragma unroll
    for (int j = 0; j < 8; ++j) {
        int idx = tid + 256 * j;
        int row = idx >> 5, ch = idx & 31;
        *(uint4*)&SH[row * 264 + ch * 8] =
            *(const uint4*)&Wb[(size_t)(ob + row) * C_ + ch * 8];
    }
    __syncthreads();

    int t = tb + 16 * w + l;

    // normalized split weights per head (lane's t)
    float lwn[SPLIT][NH];
#pragma unroll
    for (int h = 0; h < NH; ++h) {
        float lw[SPLIT], lsum = 0.f;
#pragma unroll
        for (int sp = 0; sp < SPLIT; ++sp) {
            lw[sp] = lbuf[(size_t)(sp * 8 + bz * NH + h) * T_ + t];
            lsum += lw[sp];
        }
        float inv = 1.f / lsum;
#pragma unroll
        for (int sp = 0; sp < SPLIT; ++sp) lwn[sp][h] = lw[sp] * inv;
    }

    f32x4 acc[4];
#pragma unroll
    for (int mf = 0; mf < 4; ++mf) acc[mf] = (f32x4){0.f, 0.f, 0.f, 0.f};

#pragma unroll
    for (int kk = 0; kk < 8; ++kk) {
        int c0 = 32 * kk + 8 * oct;       // k-dim index into W (c-in 0..255)
        int h  = kk >> 1;                 // head owning this c-range
        int cc = 4 * (kk & 1) + oct;      // 16B chunk within head (0..7)

        // fused combine: weighted sum of SPLIT partials -> bf16x8 B-frag
        float o[8];
#pragma unroll
        for (int j = 0; j < 8; ++j) o[j] = 0.f;
#pragma unroll
        for (int sp = 0; sp < SPLIT; ++sp) {
            const unsigned short* p = Opart +
                (((size_t)(sp * 8 + bz * NH + h) * 256 + (t >> 4)) * 8 + cc) * 128
                + (t & 15) * 8;
            uint4 u = *(const uint4*)p;
            float s = lwn[sp][h];
            o[0] += bf2f((unsigned short)(u.x & 0xffffu)) * s;
            o[1] += bf2f((unsigned short)(u.x >> 16)) * s;
            o[2] += bf2f((unsigned short)(u.y & 0xffffu)) * s;
            o[3] += bf2f((unsigned short)(u.y >> 16)) * s;
            o[4] += bf2f((unsigned short)(u.z & 0xffffu)) * s;
            o[5] += bf2f((unsigned short)(u.z >> 16)) * s;
            o[6] += bf2f((unsigned short)(u.w & 0xffffu)) * s;
            o[7] += bf2f((unsigned short)(u.w >> 16)) * s;
        }
        union { uint4 u; bf16x8 v; } pb;
        pb.u.x = pk2(o[0], o[1]); pb.u.y = pk2(o[2], o[3]);
        pb.u.z = pk2(o[4], o[5]); pb.u.w = pk2(o[6], o[7]);

#pragma unroll
        for (int mf = 0; mf < 4; ++mf) {
            bf16x8 af = *(const bf16x8*)&SH[(16 * mf + l) * 264 + c0];
            acc[mf] = __builtin_amdgcn_mfma_f32_16x16x32_bf16(af, pb.v, acc[mf], 0, 0, 0);
        }
    }

#pragma unroll
    for (int mf = 0; mf < 4; ++mf) {
#pragma unroll
        for (int r = 0; r < 4; ++r) {
            int o = ob + 16 * mf + 4 * oct + r;
            size_t idx = ((size_t)bz * C_ + o) * T_ + t;
            out[idx] = acc[mf][r] + bias[o] + xres[idx];
        }
    }
}

// ---------------------------------------------------------------------------
extern "C" void kernel_launch(void* const* d_in, const int* in_sizes, int n_in,
                              void* d_out, int out_size, void* d_ws, size_t ws_size,
                              hipStream_t stream) {
    const float* x      = (const float*)d_in[0];
    const float* norm_w = (const float*)d_in[1];
    const float* norm_b = (const float*)d_in[2];
    const float* qkv_w  = (const float*)d_in[3];
    const float* qkv_b  = (const float*)d_in[4];
    const float* proj_w = (const float*)d_in[5];
    const float* proj_b = (const float*)d_in[6];
    float* out = (float*)d_out;

    char* p = (char*)d_ws;
    unsigned short* xnT = (unsigned short*)p; p += (size_t)B_ * T_ * C_ * 2;        // 4 MB
    unsigned short* qwb = (unsigned short*)p; p += (size_t)K3C * C_ * 2;            // 384 KB
    unsigned short* pwb = (unsigned short*)p; p += (size_t)C_ * C_ * 2;             // 128 KB
    unsigned short* q_t = (unsigned short*)p; p += (size_t)B_ * NH * T_ * CH * 2;   // 4 MB
    unsigned short* k_t = (unsigned short*)p; p += (size_t)B_ * NH * T_ * CH * 2;   // 4 MB
    unsigned short* v_d = (unsigned short*)p; p += (size_t)B_ * NH * T_ * CH * 2;   // 4 MB
    unsigned short* Opart = (unsigned short*)p; p += (size_t)SPLIT * 8 * T_ * CH * 2; // 16 MB
    float* lbuf         = (float*)p;          p += (size_t)SPLIT * 8 * T_ * 4;      // 512 KB
    float* stat         = (float*)p;          p += (size_t)NSTAT * 2 * 4;           // 4 KB

    pre_kernel<<<dim3(NSTAT + NCVT), dim3(256), 0, stream>>>(
        x, stat, qkv_w, proj_w, qwb, pwb);
    gn_apply_kernel<<<dim3(B_ * GRP, GSL), dim3(256), 0, stream>>>(
        x, stat, norm_w, norm_b, xnT);
    qkv_gemm_kernel<<<dim3(T_ / 128, 12, B_), dim3(256), 0, stream>>>(
        qwb, qkv_b, xnT, q_t, k_t, v_d);
    attn_kernel<<<dim3(T_ / 128, B_ * NH, SPLIT), dim3(256), 0, stream>>>(
        q_t, k_t, v_d, Opart, lbuf);
    proj_gemm_kernel<<<dim3(T_ / 64, C_ / 64, B_), dim3(256), 0, stream>>>(
        pwb, proj_b, Opart, lbuf, x, out);
}